// Round 1
// baseline (437.892 us; speedup 1.0000x reference)
//
#include <hip/hip_runtime.h>

// RepulsionNLH: erep_atomic[a] = 0.5*BOHR * sum_{e: src[e]==a} Z[src]*Z[dst]*phi(e)*switch[e]/dist[e]
// phi(e) = sum_k CS[s12][k] * exp(-ALPHAS[s12][k] * dist[e]),  s12 = species[src] + 92*species[dst]

#define ZMAX_C 92
#define HALF_BOHR 0.264588605f   // 0.5 * 0.52917721

#if __has_builtin(__builtin_amdgcn_rcpf)
#define FAST_RCP(x) __builtin_amdgcn_rcpf(x)
#else
#define FAST_RCP(x) (1.0f / (x))
#endif

__device__ __forceinline__ void edge_work(
    int src, int dst, float r, float w,
    const int* __restrict__ species,
    const float* __restrict__ CS,
    const float* __restrict__ ALPHAS,
    float* __restrict__ out)
{
    int ss = species[src];
    int sd = species[dst];
    int prod = ss * sd;                 // species >= 0, so Z[s]*Z[d] == (float)prod exactly
    if (prod == 0) return;              // zero contribution: skip table loads + atomic
    int s12 = ss + ZMAX_C * sd;
    const float* cs = CS + 3 * s12;
    const float* al = ALPHAS + 3 * s12;
    float c0 = cs[0], c1 = cs[1], c2 = cs[2];
    float a0 = al[0], a1 = al[1], a2 = al[2];
    float phi = c0 * __expf(-a0 * r)
              + c1 * __expf(-a1 * r)
              + c2 * __expf(-a2 * r);
    float val = HALF_BOHR * (float)prod * phi * w * FAST_RCP(r);
    atomicAdd(out + src, val);
}

__global__ __launch_bounds__(256) void erep_edges(
    const int* __restrict__ edge_src,
    const int* __restrict__ edge_dst,
    const float* __restrict__ dist,
    const float* __restrict__ swt,
    const int* __restrict__ species,
    const float* __restrict__ CS,
    const float* __restrict__ ALPHAS,
    float* __restrict__ out,
    int n_edges)
{
    int t = blockIdx.x * blockDim.x + threadIdx.x;
    int i = t * 4;
    if (i + 3 < n_edges) {
        int4   s4 = *reinterpret_cast<const int4*>(edge_src + i);
        int4   d4 = *reinterpret_cast<const int4*>(edge_dst + i);
        float4 r4 = *reinterpret_cast<const float4*>(dist + i);
        float4 w4 = *reinterpret_cast<const float4*>(swt + i);
        edge_work(s4.x, d4.x, r4.x, w4.x, species, CS, ALPHAS, out);
        edge_work(s4.y, d4.y, r4.y, w4.y, species, CS, ALPHAS, out);
        edge_work(s4.z, d4.z, r4.z, w4.z, species, CS, ALPHAS, out);
        edge_work(s4.w, d4.w, r4.w, w4.w, species, CS, ALPHAS, out);
    } else if (i < n_edges) {
        for (int e = i; e < n_edges; ++e)
            edge_work(edge_src[e], edge_dst[e], dist[e], swt[e],
                      species, CS, ALPHAS, out);
    }
}

extern "C" void kernel_launch(void* const* d_in, const int* in_sizes, int n_in,
                              void* d_out, int out_size, void* d_ws, size_t ws_size,
                              hipStream_t stream)
{
    const int*   species  = (const int*)  d_in[0];
    const int*   edge_src = (const int*)  d_in[1];
    const int*   edge_dst = (const int*)  d_in[2];
    const float* dist     = (const float*)d_in[3];
    const float* swt      = (const float*)d_in[4];
    const float* CS       = (const float*)d_in[5];
    const float* ALPHAS   = (const float*)d_in[6];
    float* out = (float*)d_out;

    int n_edges = in_sizes[1];

    // Harness poisons d_out with 0xAA before every launch — zero it ourselves.
    hipMemsetAsync(d_out, 0, (size_t)out_size * sizeof(float), stream);

    int n4 = (n_edges + 3) / 4;          // 4 edges per thread
    int threads = 256;
    int blocks = (n4 + threads - 1) / threads;
    erep_edges<<<blocks, threads, 0, stream>>>(
        edge_src, edge_dst, dist, swt, species, CS, ALPHAS, out, n_edges);
}